// Round 1
// baseline (8654.118 us; speedup 1.0000x reference)
//
#include <hip/hip_runtime.h>
#include <hip/hip_bf16.h>

#define H 128

// ---------------- input projection: h[i][j] = b[j] + sum_k x[i][k]*pw[k][j]
__global__ void proj_kernel(const float* __restrict__ x, const float* __restrict__ pw,
                            const float* __restrict__ pb, float* __restrict__ hout, int N) {
    int idx = blockIdx.x * 256 + threadIdx.x;
    if (idx >= N * H) return;
    int i = idx >> 7, j = idx & 127;
    float acc = pb[j];
#pragma unroll
    for (int k = 0; k < 4; ++k) acc += x[i * 4 + k] * pw[k * H + j];
    hout[idx] = acc;
}

// ---------------- scatter-add: agg[dst[e]][:] += h[src[e]][:]
// one thread per (edge, float4-chunk): tid = e*32 + c
__global__ void scatter_add_kernel(const int* __restrict__ src, const int* __restrict__ dst,
                                   const float* __restrict__ h, float* __restrict__ agg, int total) {
    int tid = blockIdx.x * 256 + threadIdx.x;
    if (tid >= total) return;
    int e = tid >> 5, c = tid & 31;
    int s = src[e], d = dst[e];
    float4 v = *(const float4*)&h[(size_t)s * H + c * 4];
    float* out = &agg[(size_t)d * H + c * 4];
    atomicAdd(out + 0, v.x);
    atomicAdd(out + 1, v.y);
    atomicAdd(out + 2, v.z);
    atomicAdd(out + 3, v.w);
}

// ---------------- C[i][c] = relu( (A1[i][:] (+A2[i][:])) @ W + bias )
// BM=64 rows/block, 256 threads, thread tile 4 rows x 8 cols.
// A staged in LDS; W streamed from global (L2-hot, 64KB).
__global__ void gemm_relu_kernel(const float* __restrict__ A1, const float* __restrict__ A2,
                                 const float* __restrict__ W, const float* __restrict__ bias,
                                 float* __restrict__ C, int N) {
    __shared__ float As[64][H + 4];  // pad 4 -> stride 132 words (16B-aligned rows, 2-way banks = free)
    int bm = blockIdx.x * 64;
    int tid = threadIdx.x;
    // stage 64x128 fp32 tile: 2048 float4 / 256 threads = 8 reps
#pragma unroll
    for (int rep = 0; rep < 8; ++rep) {
        int lin = rep * 256 + tid;
        int r = lin >> 5;
        int c4 = lin & 31;
        int row = bm + r;
        float4 v = make_float4(0.f, 0.f, 0.f, 0.f);
        if (row < N) {
            v = *(const float4*)&A1[(size_t)row * H + c4 * 4];
            if (A2) {
                float4 w2 = *(const float4*)&A2[(size_t)row * H + c4 * 4];
                v.x += w2.x; v.y += w2.y; v.z += w2.z; v.w += w2.w;
            }
        }
        *(float4*)&As[r][c4 * 4] = v;
    }
    __syncthreads();

    int tc = tid & 15, tr = tid >> 4;
    int c0 = tc * 8, r0 = tr * 4;
    float acc[4][8] = {};

    for (int k = 0; k < H; k += 4) {
        float4 a[4];
#pragma unroll
        for (int i = 0; i < 4; ++i) a[i] = *(const float4*)&As[r0 + i][k];
#pragma unroll
        for (int kk = 0; kk < 4; ++kk) {
            float4 w0 = *(const float4*)&W[(k + kk) * H + c0];
            float4 w1 = *(const float4*)&W[(k + kk) * H + c0 + 4];
            float wv[8] = {w0.x, w0.y, w0.z, w0.w, w1.x, w1.y, w1.z, w1.w};
            float av[4];
            av[0] = (kk == 0) ? a[0].x : (kk == 1) ? a[0].y : (kk == 2) ? a[0].z : a[0].w;
            av[1] = (kk == 0) ? a[1].x : (kk == 1) ? a[1].y : (kk == 2) ? a[1].z : a[1].w;
            av[2] = (kk == 0) ? a[2].x : (kk == 1) ? a[2].y : (kk == 2) ? a[2].z : a[2].w;
            av[3] = (kk == 0) ? a[3].x : (kk == 1) ? a[3].y : (kk == 2) ? a[3].z : a[3].w;
#pragma unroll
            for (int i = 0; i < 4; ++i)
#pragma unroll
                for (int j = 0; j < 8; ++j) acc[i][j] += av[i] * wv[j];
        }
    }

#pragma unroll
    for (int i = 0; i < 4; ++i) {
        int row = bm + r0 + i;
        if (row >= N) continue;
        float4 o0, o1;
        o0.x = fmaxf(acc[i][0] + bias[c0 + 0], 0.f);
        o0.y = fmaxf(acc[i][1] + bias[c0 + 1], 0.f);
        o0.z = fmaxf(acc[i][2] + bias[c0 + 2], 0.f);
        o0.w = fmaxf(acc[i][3] + bias[c0 + 3], 0.f);
        o1.x = fmaxf(acc[i][4] + bias[c0 + 4], 0.f);
        o1.y = fmaxf(acc[i][5] + bias[c0 + 5], 0.f);
        o1.z = fmaxf(acc[i][6] + bias[c0 + 6], 0.f);
        o1.w = fmaxf(acc[i][7] + bias[c0 + 7], 0.f);
        *(float4*)&C[(size_t)row * H + c0] = o0;
        *(float4*)&C[(size_t)row * H + c0 + 4] = o1;
    }
}

// ---------------- graph boundaries: start[g] = lower_bound(batch, g); start[G] = N
__global__ void find_starts_kernel(const int* __restrict__ batch, int* __restrict__ start, int N, int G) {
    int g = blockIdx.x * 256 + threadIdx.x;
    if (g > G) return;
    if (g == G) { start[G] = N; return; }
    int lo = 0, hi = N;
    while (lo < hi) {
        int mid = (lo + hi) >> 1;
        if (batch[mid] < g) lo = mid + 1; else hi = mid;
    }
    start[g] = lo;
}

// ---------------- mean pool + shared head + energy/dipole, one block per graph
__global__ __launch_bounds__(128) void pool_head_kernel(
    const float* __restrict__ h, const int* __restrict__ start,
    const float* __restrict__ sw, const float* __restrict__ sb,
    const float* __restrict__ ew, const float* __restrict__ eb,
    const float* __restrict__ dw, const float* __restrict__ db,
    float* __restrict__ out, int G) {
    int g = blockIdx.x;
    int j = threadIdx.x;
    int s = start[g], e = start[g + 1];
    float sum = 0.f;
    for (int n = s; n < e; ++n) sum += h[(size_t)n * H + j];
    float cnt = (float)(e - s);
    __shared__ float gm[H];
    gm[j] = sum / fmaxf(cnt, 1.0f);
    __syncthreads();
    float t = sb[j];
    for (int k = 0; k < H; ++k) t += gm[k] * sw[k * H + j];
    t = fmaxf(t, 0.f);
    __shared__ float red[2][H];
    red[0][j] = t * ew[j];
    red[1][j] = t * dw[j];
    __syncthreads();
    for (int off = 64; off > 0; off >>= 1) {
        if (j < off) {
            red[0][j] += red[0][j + off];
            red[1][j] += red[1][j + off];
        }
        __syncthreads();
    }
    if (j == 0) {
        out[g] = red[0][0] + eb[0];
        out[G + g] = red[1][0] + db[0];
    }
}

extern "C" void kernel_launch(void* const* d_in, const int* in_sizes, int n_in,
                              void* d_out, int out_size, void* d_ws, size_t ws_size,
                              hipStream_t stream) {
    const float* x      = (const float*)d_in[0];
    const int*   ei     = (const int*)d_in[1];
    const int*   batch  = (const int*)d_in[2];
    const float* proj_w = (const float*)d_in[3];
    const float* proj_b = (const float*)d_in[4];
    const float* cw1    = (const float*)d_in[5];
    const float* cb1    = (const float*)d_in[6];
    const float* cw2    = (const float*)d_in[7];
    const float* cb2    = (const float*)d_in[8];
    const float* sw     = (const float*)d_in[9];
    const float* sb     = (const float*)d_in[10];
    const float* ew     = (const float*)d_in[11];
    const float* eb     = (const float*)d_in[12];
    const float* dw     = (const float*)d_in[13];
    const float* db     = (const float*)d_in[14];

    int N = in_sizes[0] / 4;   // D_IN = 4
    int E = in_sizes[1] / 2;
    int G = out_size / 2;

    const int* src = ei;
    const int* dst = ei + E;

    float* h   = (float*)d_ws;
    float* buf = h + (size_t)N * H;      // agg, then MLP hidden (row-disjoint overwrite is safe)
    int* start = (int*)(buf + (size_t)N * H);

    float* out = (float*)d_out;

    proj_kernel<<<(N * H + 255) / 256, 256, 0, stream>>>(x, proj_w, proj_b, h, N);

    int gemm_blocks = (N + 63) / 64;
    int scat_total = E * 32;
    int scat_blocks = (scat_total + 255) / 256;

    for (int l = 0; l < 3; ++l) {
        hipMemsetAsync(buf, 0, (size_t)N * H * sizeof(float), stream);
        scatter_add_kernel<<<scat_blocks, 256, 0, stream>>>(src, dst, h, buf, scat_total);
        // GEMM1: relu((h + agg) @ W1 + b1) -> buf (overwrites agg; each block only touches its own rows)
        gemm_relu_kernel<<<gemm_blocks, 256, 0, stream>>>(h, buf, cw1 + (size_t)l * H * H, cb1 + l * H, buf, N);
        // GEMM2: relu(buf @ W2 + b2) -> h
        gemm_relu_kernel<<<gemm_blocks, 256, 0, stream>>>(buf, nullptr, cw2 + (size_t)l * H * H, cb2 + l * H, h, N);
    }

    find_starts_kernel<<<(G + 1 + 255) / 256, 256, 0, stream>>>(batch, start, N, G);
    pool_head_kernel<<<G, 128, 0, stream>>>(h, start, sw, sb, ew, eb, dw, db, out, G);
}

// Round 2
// 1146.736 us; speedup vs baseline: 7.5467x; 7.5467x over previous
//
#include <hip/hip_runtime.h>
#include <hip/hip_bf16.h>

#define H 128

// ---------------- input projection: h[i][j] = b[j] + sum_k x[i][k]*pw[k][j]
__global__ void proj_kernel(const float* __restrict__ x, const float* __restrict__ pw,
                            const float* __restrict__ pb, float* __restrict__ hout, int N) {
    int idx = blockIdx.x * 256 + threadIdx.x;
    if (idx >= N * H) return;
    int i = idx >> 7, j = idx & 127;
    float acc = pb[j];
#pragma unroll
    for (int k = 0; k < 4; ++k) acc += x[i * 4 + k] * pw[k * H + j];
    hout[idx] = acc;
}

// ================= CSR build (by dst) =================
__global__ void count_kernel(const int* __restrict__ dst, int* __restrict__ cnt, int E) {
    int e = blockIdx.x * 256 + threadIdx.x;
    if (e < E) atomicAdd(&cnt[dst[e]], 1);
}

// in-place exclusive scan, 1024 elems/block; block totals to bsum
__global__ void scan_block_kernel(int* __restrict__ data, int* __restrict__ bsum, int n) {
    __shared__ int s[1024];
    int tid = threadIdx.x;
    int i = blockIdx.x * 1024 + tid;
    int v = (i < n) ? data[i] : 0;
    s[tid] = v;
    __syncthreads();
    for (int off = 1; off < 1024; off <<= 1) {
        int t = (tid >= off) ? s[tid - off] : 0;
        __syncthreads();
        s[tid] += t;
        __syncthreads();
    }
    if (i < n) data[i] = s[tid] - v;  // exclusive
    if (tid == 1023) bsum[blockIdx.x] = s[1023];
}

// single-block scan of block sums (nb <= 128); writes grand total to offs[N]
__global__ void scan_sums_kernel(int* __restrict__ bsum, int nb, int* __restrict__ offs, int N) {
    __shared__ int s[128];
    int tid = threadIdx.x;
    int v = (tid < nb) ? bsum[tid] : 0;
    s[tid] = v;
    __syncthreads();
    for (int off = 1; off < 128; off <<= 1) {
        int t = (tid >= off) ? s[tid - off] : 0;
        __syncthreads();
        s[tid] += t;
        __syncthreads();
    }
    if (tid < nb) bsum[tid] = s[tid] - v;  // exclusive
    if (tid == nb - 1) offs[N] = s[tid];   // total
}

__global__ void scan_add_kernel(int* __restrict__ data, const int* __restrict__ bsum, int n) {
    int i = blockIdx.x * 1024 + threadIdx.x;
    if (i < n) data[i] += bsum[blockIdx.x];
}

// fill: bump offs[d] (it becomes the END pointer of node d == start of node d+1)
__global__ void fill_kernel(const int* __restrict__ src, const int* __restrict__ dst,
                            int* __restrict__ offs, int* __restrict__ esrc, int E) {
    int e = blockIdx.x * 256 + threadIdx.x;
    if (e < E) {
        int p = atomicAdd(&offs[dst[e]], 1);
        esrc[p] = src[e];
    }
}

// ---------------- gather aggregation: agg[n][:] = sum_{j in nbrs(n)} h[j][:]
// thread = (node, float4 lane); after fill, node n spans [offs[n-1], offs[n])
__global__ void gather_agg_kernel(const int* __restrict__ offs, const int* __restrict__ esrc,
                                  const float* __restrict__ h, float* __restrict__ agg, int N) {
    int tid = blockIdx.x * 256 + threadIdx.x;
    if (tid >= N * 32) return;
    int node = tid >> 5, c = (tid & 31) * 4;
    int s = (node == 0) ? 0 : offs[node - 1];
    int e = offs[node];
    float4 acc = make_float4(0.f, 0.f, 0.f, 0.f);
    for (int i = s; i < e; ++i) {
        float4 v = *(const float4*)&h[(size_t)esrc[i] * H + c];
        acc.x += v.x; acc.y += v.y; acc.z += v.z; acc.w += v.w;
    }
    *(float4*)&agg[(size_t)node * H + c] = acc;
}

// ---------------- C[i][c] = relu( (A1[i][:] (+A2[i][:])) @ W + bias )
__global__ void gemm_relu_kernel(const float* __restrict__ A1, const float* __restrict__ A2,
                                 const float* __restrict__ W, const float* __restrict__ bias,
                                 float* __restrict__ C, int N) {
    __shared__ float As[64][H + 4];
    int bm = blockIdx.x * 64;
    int tid = threadIdx.x;
#pragma unroll
    for (int rep = 0; rep < 8; ++rep) {
        int lin = rep * 256 + tid;
        int r = lin >> 5;
        int c4 = lin & 31;
        int row = bm + r;
        float4 v = make_float4(0.f, 0.f, 0.f, 0.f);
        if (row < N) {
            v = *(const float4*)&A1[(size_t)row * H + c4 * 4];
            if (A2) {
                float4 w2 = *(const float4*)&A2[(size_t)row * H + c4 * 4];
                v.x += w2.x; v.y += w2.y; v.z += w2.z; v.w += w2.w;
            }
        }
        *(float4*)&As[r][c4 * 4] = v;
    }
    __syncthreads();

    int tc = tid & 15, tr = tid >> 4;
    int c0 = tc * 8, r0 = tr * 4;
    float acc[4][8] = {};

    for (int k = 0; k < H; k += 4) {
        float4 a[4];
#pragma unroll
        for (int i = 0; i < 4; ++i) a[i] = *(const float4*)&As[r0 + i][k];
#pragma unroll
        for (int kk = 0; kk < 4; ++kk) {
            float4 w0 = *(const float4*)&W[(k + kk) * H + c0];
            float4 w1 = *(const float4*)&W[(k + kk) * H + c0 + 4];
            float wv[8] = {w0.x, w0.y, w0.z, w0.w, w1.x, w1.y, w1.z, w1.w};
            float av[4];
            av[0] = (kk == 0) ? a[0].x : (kk == 1) ? a[0].y : (kk == 2) ? a[0].z : a[0].w;
            av[1] = (kk == 0) ? a[1].x : (kk == 1) ? a[1].y : (kk == 2) ? a[1].z : a[1].w;
            av[2] = (kk == 0) ? a[2].x : (kk == 1) ? a[2].y : (kk == 2) ? a[2].z : a[2].w;
            av[3] = (kk == 0) ? a[3].x : (kk == 1) ? a[3].y : (kk == 2) ? a[3].z : a[3].w;
#pragma unroll
            for (int i = 0; i < 4; ++i)
#pragma unroll
                for (int j = 0; j < 8; ++j) acc[i][j] += av[i] * wv[j];
        }
    }

#pragma unroll
    for (int i = 0; i < 4; ++i) {
        int row = bm + r0 + i;
        if (row >= N) continue;
        float4 o0, o1;
        o0.x = fmaxf(acc[i][0] + bias[c0 + 0], 0.f);
        o0.y = fmaxf(acc[i][1] + bias[c0 + 1], 0.f);
        o0.z = fmaxf(acc[i][2] + bias[c0 + 2], 0.f);
        o0.w = fmaxf(acc[i][3] + bias[c0 + 3], 0.f);
        o1.x = fmaxf(acc[i][4] + bias[c0 + 4], 0.f);
        o1.y = fmaxf(acc[i][5] + bias[c0 + 5], 0.f);
        o1.z = fmaxf(acc[i][6] + bias[c0 + 6], 0.f);
        o1.w = fmaxf(acc[i][7] + bias[c0 + 7], 0.f);
        *(float4*)&C[(size_t)row * H + c0] = o0;
        *(float4*)&C[(size_t)row * H + c0 + 4] = o1;
    }
}

// ---------------- graph boundaries
__global__ void find_starts_kernel(const int* __restrict__ batch, int* __restrict__ start, int N, int G) {
    int g = blockIdx.x * 256 + threadIdx.x;
    if (g > G) return;
    if (g == G) { start[G] = N; return; }
    int lo = 0, hi = N;
    while (lo < hi) {
        int mid = (lo + hi) >> 1;
        if (batch[mid] < g) lo = mid + 1; else hi = mid;
    }
    start[g] = lo;
}

// ---------------- mean pool + shared head + energy/dipole, one block per graph
__global__ __launch_bounds__(128) void pool_head_kernel(
    const float* __restrict__ h, const int* __restrict__ start,
    const float* __restrict__ sw, const float* __restrict__ sb,
    const float* __restrict__ ew, const float* __restrict__ eb,
    const float* __restrict__ dw, const float* __restrict__ db,
    float* __restrict__ out, int G) {
    int g = blockIdx.x;
    int j = threadIdx.x;
    int s = start[g], e = start[g + 1];
    float sum = 0.f;
    for (int n = s; n < e; ++n) sum += h[(size_t)n * H + j];
    float cnt = (float)(e - s);
    __shared__ float gm[H];
    gm[j] = sum / fmaxf(cnt, 1.0f);
    __syncthreads();
    float t = sb[j];
    for (int k = 0; k < H; ++k) t += gm[k] * sw[k * H + j];
    t = fmaxf(t, 0.f);
    __shared__ float red[2][H];
    red[0][j] = t * ew[j];
    red[1][j] = t * dw[j];
    __syncthreads();
    for (int off = 64; off > 0; off >>= 1) {
        if (j < off) {
            red[0][j] += red[0][j + off];
            red[1][j] += red[1][j + off];
        }
        __syncthreads();
    }
    if (j == 0) {
        out[g] = red[0][0] + eb[0];
        out[G + g] = red[1][0] + db[0];
    }
}

extern "C" void kernel_launch(void* const* d_in, const int* in_sizes, int n_in,
                              void* d_out, int out_size, void* d_ws, size_t ws_size,
                              hipStream_t stream) {
    const float* x      = (const float*)d_in[0];
    const int*   ei     = (const int*)d_in[1];
    const int*   batch  = (const int*)d_in[2];
    const float* proj_w = (const float*)d_in[3];
    const float* proj_b = (const float*)d_in[4];
    const float* cw1    = (const float*)d_in[5];
    const float* cb1    = (const float*)d_in[6];
    const float* cw2    = (const float*)d_in[7];
    const float* cb2    = (const float*)d_in[8];
    const float* sw     = (const float*)d_in[9];
    const float* sb     = (const float*)d_in[10];
    const float* ew     = (const float*)d_in[11];
    const float* eb     = (const float*)d_in[12];
    const float* dw     = (const float*)d_in[13];
    const float* db     = (const float*)d_in[14];

    int N = in_sizes[0] / 4;   // D_IN = 4
    int E = in_sizes[1] / 2;
    int G = out_size / 2;

    const int* src = ei;
    const int* dst = ei + E;

    // workspace layout
    float* h    = (float*)d_ws;                       // N*H f32
    float* buf  = h + (size_t)N * H;                  // N*H f32 (agg / MLP hidden)
    int*   offs = (int*)(buf + (size_t)N * H);        // N+1 ints
    int*   bsum = offs + (N + 1);                     // 128 ints
    int*   start = bsum + 128;                        // G+1 ints
    int*   esrc = start + (G + 1);                    // E ints

    float* out = (float*)d_out;

    // ---- CSR build (once per call) ----
    hipMemsetAsync(offs, 0, (size_t)(N + 1) * sizeof(int), stream);
    count_kernel<<<(E + 255) / 256, 256, 0, stream>>>(dst, offs, E);
    int nb = (N + 1023) / 1024;
    scan_block_kernel<<<nb, 1024, 0, stream>>>(offs, bsum, N);
    scan_sums_kernel<<<1, 128, 0, stream>>>(bsum, nb, offs, N);
    scan_add_kernel<<<nb, 1024, 0, stream>>>(offs, bsum, N);
    fill_kernel<<<(E + 255) / 256, 256, 0, stream>>>(src, dst, offs, esrc, E);
    // offs[n] is now the END of node n's range; start = (n==0)?0:offs[n-1]

    proj_kernel<<<(N * H + 255) / 256, 256, 0, stream>>>(x, proj_w, proj_b, h, N);

    int gemm_blocks = (N + 63) / 64;
    int gather_blocks = (N * 32 + 255) / 256;

    for (int l = 0; l < 3; ++l) {
        gather_agg_kernel<<<gather_blocks, 256, 0, stream>>>(offs, esrc, h, buf, N);
        gemm_relu_kernel<<<gemm_blocks, 256, 0, stream>>>(h, buf, cw1 + (size_t)l * H * H, cb1 + l * H, buf, N);
        gemm_relu_kernel<<<gemm_blocks, 256, 0, stream>>>(buf, nullptr, cw2 + (size_t)l * H * H, cb2 + l * H, h, N);
    }

    find_starts_kernel<<<(G + 1 + 255) / 256, 256, 0, stream>>>(batch, start, N, G);
    pool_head_kernel<<<G, 128, 0, stream>>>(h, start, sw, sb, ew, eb, dw, db, out, G);
}

// Round 3
// 610.245 us; speedup vs baseline: 14.1814x; 1.8791x over previous
//
#include <hip/hip_runtime.h>
#include <hip/hip_bf16.h>

#define H 128

typedef short short8 __attribute__((ext_vector_type(8)));
typedef float f32x4 __attribute__((ext_vector_type(4)));

__device__ __forceinline__ float bf2f(unsigned short u) {
    union { unsigned int i; float f; } c; c.i = ((unsigned int)u) << 16; return c.f;
}
__device__ __forceinline__ unsigned short f2bf(float f) {
    return __builtin_bit_cast(unsigned short, __float2bfloat16(f));
}

// ---------------- weight prep: wt[m][o][i] = bf16(W_m[i][o]), m in 0..5 (3x cw1, 3x cw2)
__global__ void prep_w_kernel(const float* __restrict__ cw1, const float* __restrict__ cw2,
                              unsigned short* __restrict__ wt, int total) {
    int idx = blockIdx.x * 256 + threadIdx.x;
    if (idx >= total) return;
    int m = idx >> 14;
    int o = (idx >> 7) & 127;
    int i = idx & 127;
    const float* srcp = (m < 3) ? (cw1 + (size_t)m * H * H) : (cw2 + (size_t)(m - 3) * H * H);
    wt[idx] = f2bf(srcp[i * H + o]);
}

// ---------------- input projection -> bf16 h
__global__ void proj_kernel(const float* __restrict__ x, const float* __restrict__ pw,
                            const float* __restrict__ pb, unsigned short* __restrict__ hout, int N) {
    int tid = blockIdx.x * 256 + threadIdx.x;
    if (tid >= N * 16) return;
    int i = tid >> 4, c = (tid & 15) * 8;
    float4 xv = *(const float4*)&x[i * 4];
    float acc[8];
#pragma unroll
    for (int j = 0; j < 8; ++j)
        acc[j] = pb[c + j] + xv.x * pw[0 * H + c + j] + xv.y * pw[1 * H + c + j]
               + xv.z * pw[2 * H + c + j] + xv.w * pw[3 * H + c + j];
    short8 o;
#pragma unroll
    for (int j = 0; j < 8; ++j) o[j] = (short)f2bf(acc[j]);
    *(short8*)&hout[(size_t)i * H + c] = o;
}

// ================= CSR build (by dst) =================
__global__ void count_kernel(const int* __restrict__ dst, int* __restrict__ cnt, int E) {
    int e = blockIdx.x * 256 + threadIdx.x;
    if (e < E) atomicAdd(&cnt[dst[e]], 1);
}

__global__ void scan_block_kernel(int* __restrict__ data, int* __restrict__ bsum, int n) {
    __shared__ int s[1024];
    int tid = threadIdx.x;
    int i = blockIdx.x * 1024 + tid;
    int v = (i < n) ? data[i] : 0;
    s[tid] = v;
    __syncthreads();
    for (int off = 1; off < 1024; off <<= 1) {
        int t = (tid >= off) ? s[tid - off] : 0;
        __syncthreads();
        s[tid] += t;
        __syncthreads();
    }
    if (i < n) data[i] = s[tid] - v;
    if (tid == 1023) bsum[blockIdx.x] = s[1023];
}

__global__ void scan_sums_kernel(int* __restrict__ bsum, int nb, int* __restrict__ offs, int N) {
    __shared__ int s[128];
    int tid = threadIdx.x;
    int v = (tid < nb) ? bsum[tid] : 0;
    s[tid] = v;
    __syncthreads();
    for (int off = 1; off < 128; off <<= 1) {
        int t = (tid >= off) ? s[tid - off] : 0;
        __syncthreads();
        s[tid] += t;
        __syncthreads();
    }
    if (tid < nb) bsum[tid] = s[tid] - v;
    if (tid == nb - 1) offs[N] = s[tid];
}

__global__ void scan_add_kernel(int* __restrict__ data, const int* __restrict__ bsum, int n) {
    int i = blockIdx.x * 1024 + threadIdx.x;
    if (i < n) data[i] += bsum[blockIdx.x];
}

__global__ void fill_kernel(const int* __restrict__ src, const int* __restrict__ dst,
                            int* __restrict__ offs, int* __restrict__ esrc, int E) {
    int e = blockIdx.x * 256 + threadIdx.x;
    if (e < E) {
        int p = atomicAdd(&offs[dst[e]], 1);
        esrc[p] = src[e];
    }
}

// ---------------- gather aggregation (bf16 in, fp32 acc, bf16 out)
__global__ void gather_agg_kernel(const int* __restrict__ offs, const int* __restrict__ esrc,
                                  const unsigned short* __restrict__ h, unsigned short* __restrict__ agg, int N) {
    int tid = blockIdx.x * 256 + threadIdx.x;
    if (tid >= N * 16) return;
    int node = tid >> 4, c = (tid & 15) * 8;
    int s = (node == 0) ? 0 : offs[node - 1];
    int e = offs[node];
    float acc[8] = {};
    for (int i = s; i < e; ++i) {
        short8 v = *(const short8*)&h[(size_t)esrc[i] * H + c];
#pragma unroll
        for (int j = 0; j < 8; ++j) acc[j] += bf2f((unsigned short)v[j]);
    }
    short8 o;
#pragma unroll
    for (int j = 0; j < 8; ++j) o[j] = (short)f2bf(acc[j]);
    *(short8*)&agg[(size_t)node * H + c] = o;
}

// ---------------- MFMA GEMM: C = relu((A1 (+A2)) @ Wt^T + bias), all bf16 except bias/acc
// block = 64 rows, 256 threads = 4 waves, each wave 32 rows x 64 cols.
template <bool HAS_A2>
__global__ __launch_bounds__(256) void gemm_mfma_kernel(
    const unsigned short* __restrict__ A1, const unsigned short* __restrict__ A2,
    const unsigned short* __restrict__ Wt, const float* __restrict__ bias,
    unsigned short* __restrict__ C, int N) {
    __shared__ unsigned short As[64 * H];   // XOR-swizzled, row stride 256B
    __shared__ unsigned short Ws[H * H];    // XOR-swizzled, row(=out col) stride 256B
    int bm = blockIdx.x * 64;
    int tid = threadIdx.x;

    // stage A tile: 64 rows x 16 chunks of 16B
#pragma unroll
    for (int rep = 0; rep < 4; ++rep) {
        int lin = rep * 256 + tid;
        int r = lin >> 4, cb = lin & 15;
        int row = bm + r;
        short8 v = {};
        if (row < N) {
            v = *(const short8*)&A1[(size_t)row * H + cb * 8];
            if (HAS_A2) {
                short8 v2 = *(const short8*)&A2[(size_t)row * H + cb * 8];
#pragma unroll
                for (int j = 0; j < 8; ++j)
                    v[j] = (short)f2bf(bf2f((unsigned short)v[j]) + bf2f((unsigned short)v2[j]));
            }
        }
        int byte = r * 256 + ((cb * 16) ^ ((r & 7) << 4));
        *(short8*)((char*)As + byte) = v;
    }
    // stage W tile: 128 out-cols x 16 chunks
#pragma unroll
    for (int rep = 0; rep < 8; ++rep) {
        int lin = rep * 256 + tid;
        int o = lin >> 4, cb = lin & 15;
        short8 v = *(const short8*)&Wt[(size_t)o * H + cb * 8];
        int byte = o * 256 + ((cb * 16) ^ ((o & 7) << 4));
        *(short8*)((char*)Ws + byte) = v;
    }
    __syncthreads();

    int lane = tid & 63;
    int w = tid >> 6;
    int wr = (w >> 1) * 32;
    int wc = (w & 1) * 64;
    int lrow = lane & 15, kg = lane >> 4;

    short8 a[2][4];
#pragma unroll
    for (int rt = 0; rt < 2; ++rt)
#pragma unroll
        for (int ks = 0; ks < 4; ++ks) {
            int r = wr + rt * 16 + lrow;
            int kb = ks * 64 + kg * 16;
            a[rt][ks] = *(short8*)((char*)As + r * 256 + (kb ^ ((r & 7) << 4)));
        }

    f32x4 acc[2][4] = {};
#pragma unroll
    for (int ct = 0; ct < 4; ++ct) {
#pragma unroll
        for (int ks = 0; ks < 4; ++ks) {
            int o = wc + ct * 16 + lrow;
            int kb = ks * 64 + kg * 16;
            short8 b = *(short8*)((char*)Ws + o * 256 + (kb ^ ((o & 7) << 4)));
            acc[0][ct] = __builtin_amdgcn_mfma_f32_16x16x32_bf16(a[0][ks], b, acc[0][ct], 0, 0, 0);
            acc[1][ct] = __builtin_amdgcn_mfma_f32_16x16x32_bf16(a[1][ks], b, acc[1][ct], 0, 0, 0);
        }
    }

#pragma unroll
    for (int rt = 0; rt < 2; ++rt)
#pragma unroll
        for (int ct = 0; ct < 4; ++ct)
#pragma unroll
            for (int r = 0; r < 4; ++r) {
                int row = bm + wr + rt * 16 + kg * 4 + r;
                int col = wc + ct * 16 + lrow;
                if (row < N) {
                    float v = fmaxf(acc[rt][ct][r] + bias[col], 0.f);
                    C[(size_t)row * H + col] = f2bf(v);
                }
            }
}

// ---------------- graph boundaries
__global__ void find_starts_kernel(const int* __restrict__ batch, int* __restrict__ start, int N, int G) {
    int g = blockIdx.x * 256 + threadIdx.x;
    if (g > G) return;
    if (g == G) { start[G] = N; return; }
    int lo = 0, hi = N;
    while (lo < hi) {
        int mid = (lo + hi) >> 1;
        if (batch[mid] < g) lo = mid + 1; else hi = mid;
    }
    start[g] = lo;
}

// ---------------- mean pool + shared head, one block per graph
__global__ __launch_bounds__(128) void pool_head_kernel(
    const unsigned short* __restrict__ h, const int* __restrict__ start,
    const float* __restrict__ sw, const float* __restrict__ sb,
    const float* __restrict__ ew, const float* __restrict__ eb,
    const float* __restrict__ dw, const float* __restrict__ db,
    float* __restrict__ out, int G) {
    int g = blockIdx.x;
    int j = threadIdx.x;
    int s = start[g], e = start[g + 1];
    float sum = 0.f;
    for (int n = s; n < e; ++n) sum += bf2f(h[(size_t)n * H + j]);
    float cnt = (float)(e - s);
    __shared__ float gm[H];
    gm[j] = sum / fmaxf(cnt, 1.0f);
    __syncthreads();
    float t = sb[j];
    for (int k = 0; k < H; ++k) t += gm[k] * sw[k * H + j];
    t = fmaxf(t, 0.f);
    __shared__ float red[2][H];
    red[0][j] = t * ew[j];
    red[1][j] = t * dw[j];
    __syncthreads();
    for (int off = 64; off > 0; off >>= 1) {
        if (j < off) {
            red[0][j] += red[0][j + off];
            red[1][j] += red[1][j + off];
        }
        __syncthreads();
    }
    if (j == 0) {
        out[g] = red[0][0] + eb[0];
        out[G + g] = red[1][0] + db[0];
    }
}

extern "C" void kernel_launch(void* const* d_in, const int* in_sizes, int n_in,
                              void* d_out, int out_size, void* d_ws, size_t ws_size,
                              hipStream_t stream) {
    const float* x      = (const float*)d_in[0];
    const int*   ei     = (const int*)d_in[1];
    const int*   batch  = (const int*)d_in[2];
    const float* proj_w = (const float*)d_in[3];
    const float* proj_b = (const float*)d_in[4];
    const float* cw1    = (const float*)d_in[5];
    const float* cb1    = (const float*)d_in[6];
    const float* cw2    = (const float*)d_in[7];
    const float* cb2    = (const float*)d_in[8];
    const float* sw     = (const float*)d_in[9];
    const float* sb     = (const float*)d_in[10];
    const float* ew     = (const float*)d_in[11];
    const float* eb     = (const float*)d_in[12];
    const float* dw     = (const float*)d_in[13];
    const float* db     = (const float*)d_in[14];

    int N = in_sizes[0] / 4;
    int E = in_sizes[1] / 2;
    int G = out_size / 2;

    const int* src = ei;
    const int* dst = ei + E;

    // workspace layout (16B alignment maintained)
    unsigned short* h   = (unsigned short*)d_ws;          // N*H bf16
    unsigned short* buf = h + (size_t)N * H;              // N*H bf16 (agg / hidden)
    unsigned short* wt  = buf + (size_t)N * H;            // 6*H*H bf16
    int* offs  = (int*)(wt + 6 * H * H);                  // N+1
    int* bsum  = offs + (N + 1);                          // 128
    int* start = bsum + 128;                              // G+1
    int* esrc  = start + (G + 1);                         // E

    float* out = (float*)d_out;

    // ---- CSR build ----
    hipMemsetAsync(offs, 0, (size_t)(N + 1) * sizeof(int), stream);
    count_kernel<<<(E + 255) / 256, 256, 0, stream>>>(dst, offs, E);
    int nb = (N + 1023) / 1024;
    scan_block_kernel<<<nb, 1024, 0, stream>>>(offs, bsum, N);
    scan_sums_kernel<<<1, 128, 0, stream>>>(bsum, nb, offs, N);
    scan_add_kernel<<<nb, 1024, 0, stream>>>(offs, bsum, N);
    fill_kernel<<<(E + 255) / 256, 256, 0, stream>>>(src, dst, offs, esrc, E);

    // ---- weights prep + projection ----
    prep_w_kernel<<<(6 * H * H + 255) / 256, 256, 0, stream>>>(cw1, cw2, wt, 6 * H * H);
    proj_kernel<<<(N * 16 + 255) / 256, 256, 0, stream>>>(x, proj_w, proj_b, h, N);

    int gemm_blocks = (N + 63) / 64;
    int gather_blocks = (N * 16 + 255) / 256;

    for (int l = 0; l < 3; ++l) {
        gather_agg_kernel<<<gather_blocks, 256, 0, stream>>>(offs, esrc, h, buf, N);
        gemm_mfma_kernel<true><<<gemm_blocks, 256, 0, stream>>>(
            h, buf, wt + (size_t)l * H * H, cb1 + l * H, buf, N);
        gemm_mfma_kernel<false><<<gemm_blocks, 256, 0, stream>>>(
            buf, nullptr, wt + (size_t)(3 + l) * H * H, cb2 + l * H, h, N);
    }

    find_starts_kernel<<<(G + 1 + 255) / 256, 256, 0, stream>>>(batch, start, N, G);
    pool_head_kernel<<<G, 128, 0, stream>>>(h, start, sw, sb, ew, eb, dw, db, out, G);
}